// Round 14
// baseline (337.750 us; speedup 1.0000x reference)
//
#include <hip/hip_runtime.h>
#include <hip/hip_bf16.h>

typedef __bf16 bf16x8 __attribute__((ext_vector_type(8)));
typedef float  f32x4  __attribute__((ext_vector_type(4)));

#define HID   256
#define BM    32
#define ROWF  256   // floats per LDS row (fp32 tiles, XOR-swizzled chunks)
#define TPB   8     // tiles per persistent block

// gate order: 0=ir 1=iz 2=in 3=hz 4=hn
// ---- prepack weights fp32 -> bf16 in MFMA-fragment order --------------------
// fragment (ks,g,cb): lane l, elem j = W_g[cb*16 + (l&15)][ks*32 + (l>>4)*8 + j]
// stored at wb[((ks*5+g)*16+cb)*512 + l*8 + j]  -> 1KB contiguous per fragment
__global__ void __launch_bounds__(256) prepack_frag(
    const float* __restrict__ w0, const float* __restrict__ w1,
    const float* __restrict__ w2, const float* __restrict__ w3,
    const float* __restrict__ w4, __bf16* __restrict__ wb)
{
    int t    = blockIdx.x * 256 + threadIdx.x;   // 40960 total
    int lane = t & 63;
    int cb   = (t >> 6) & 15;
    int gk   = t >> 10;                          // ks*5 + g
    int g    = gk % 5;
    int ks   = gk / 5;
    const float* W = g == 0 ? w0 : g == 1 ? w1 : g == 2 ? w2 : g == 3 ? w3 : w4;
    int row = cb * 16 + (lane & 15);
    int k0  = ks * 32 + (lane >> 4) * 8;
    float4 p = *(const float4*)(W + row * HID + k0);
    float4 q = *(const float4*)(W + row * HID + k0 + 4);
    bf16x8 o;
    o[0]=(__bf16)p.x; o[1]=(__bf16)p.y; o[2]=(__bf16)p.z; o[3]=(__bf16)p.w;
    o[4]=(__bf16)q.x; o[5]=(__bf16)q.y; o[6]=(__bf16)q.z; o[7]=(__bf16)q.w;
    *(bf16x8*)(wb + (size_t)t * 8) = o;
}

#define MFMA1(D, A_, B_) D = __builtin_amdgcn_mfma_f32_16x16x32_bf16(A_, B_, D, 0, 0, 0)

// 12 MFMAs for row-block MF. Same-acc dependency distance >= 3.
#define MFMA12(MF, AX, AH, B_) do {                                     \
    _Pragma("unroll")                                                   \
    for (int nf = 0; nf < 2; ++nf) {                                    \
        MFMA1(az[MF][nf],  AX, B_[2 + nf]);                             \
        MFMA1(ar[MF][nf],  AX, B_[0 + nf]);                             \
        MFMA1(anx[MF][nf], AX, B_[4 + nf]);                             \
        MFMA1(az[MF][nf],  AH, B_[6 + nf]);                             \
        MFMA1(ar[MF][nf],  AH, B_[6 + nf]);                             \
        MFMA1(anh[MF][nf], AH, B_[8 + nf]);                             \
    }                                                                   \
} while (0)

// load the 10 B-fragments for K-step KK (each a contiguous 1KB burst)
#define LOADB(DST, KK) do {                                             \
    _Pragma("unroll")                                                   \
    for (int g = 0; g < 5; ++g)                                         \
        _Pragma("unroll")                                               \
        for (int nf = 0; nf < 2; ++nf)                                  \
            DST[g * 2 + nf] =                                           \
                *(const bf16x8*)(wbase + ((KK) * 5 + g) * 8192 + nf * 512); \
} while (0)

// fallback: load fp32 weights JIT and convert (correctness path)
#define LOADB_SLOW(DST, KK) do {                                        \
    _Pragma("unroll")                                                   \
    for (int g = 0; g < 5; ++g)                                         \
        _Pragma("unroll")                                               \
        for (int nf = 0; nf < 2; ++nf) {                                \
            const float* pp = wsrc[g] + ((wn * 2 + nf) * 16 + lr) * HID + (KK) * 32 + lg * 8; \
            float4 c0 = *(const float4*)(pp), c1 = *(const float4*)(pp + 4); \
            bf16x8 u;                                                   \
            u[0]=(__bf16)c0.x; u[1]=(__bf16)c0.y; u[2]=(__bf16)c0.z; u[3]=(__bf16)c0.w; \
            u[4]=(__bf16)c1.x; u[5]=(__bf16)c1.y; u[6]=(__bf16)c1.z; u[7]=(__bf16)c1.w; \
            DST[g * 2 + nf] = u;                                        \
        }                                                               \
} while (0)

// async global->LDS DMA: 16B/lane, per-lane SOURCE addr, uniform LDS base
#define G2L16(SRC, DST) \
    __builtin_amdgcn_global_load_lds( \
        (const __attribute__((address_space(1))) void*)(SRC), \
        (__attribute__((address_space(3))) void*)(DST), 16, 0, 0)

// stage one x-row and one h-row (J=0..3) of the NEXT tile into XW/HW.
// Swizzle: LDS chunk i of row r holds global chunk i^(r&7)  [both-sides rule]
#define STAGE2(XW, HW, J) do {                                          \
    int r_ = wn * 4 + (J);                                              \
    int sc = 4 * (lane ^ (r_ & 7));                                     \
    G2L16(x + (size_t)(prow0 + r_) * HID + sc, (XW) + r_ * ROWF);       \
    G2L16(h + (size_t)(prow0 + r_) * HID + sc, (HW) + r_ * ROWF);       \
} while (0)

// A-fragment: rows MF*16+lr of fp32 tile TF, k = KS*32+lg*8..+7, swizzled read
#define LDA(DST, TF, MF, KS) do {                                       \
    int r_  = (MF) * 16 + lr;                                           \
    int c0_ = 8 * (KS) + 2 * lg;                                        \
    const float* bp_ = (TF) + r_ * ROWF;                                \
    f32x4 v0_ = *(const f32x4*)(bp_ + 4 * ((c0_)     ^ (r_ & 7)));      \
    f32x4 v1_ = *(const f32x4*)(bp_ + 4 * ((c0_ + 1) ^ (r_ & 7)));      \
    DST[0]=(__bf16)v0_[0]; DST[1]=(__bf16)v0_[1]; DST[2]=(__bf16)v0_[2]; DST[3]=(__bf16)v0_[3]; \
    DST[4]=(__bf16)v1_[0]; DST[5]=(__bf16)v1_[1]; DST[6]=(__bf16)v1_[2]; DST[7]=(__bf16)v1_[3]; \
} while (0)

// MFMA cluster for K-step KC: 8 ds_read_b128 + cvt + 24 MFMA
#define CLUSTER(XF, HF, B_, KC) do {                                    \
    bf16x8 a0x, a0h, a1x, a1h;                                          \
    LDA(a0x, XF, 0, KC); LDA(a0h, HF, 0, KC);                           \
    LDA(a1x, XF, 1, KC); LDA(a1h, HF, 1, KC);                           \
    MFMA12(0, a0x, a0h, B_);                                            \
    MFMA12(1, a1x, a1h, B_);                                            \
} while (0)

// K-step pair: static Ba/Bb double-buffer, wave-staggered K (start = wn).
// At I2==3 the Ba-prefetch wraps to wn == next tile's first set.
#define KPAIR(XF, HF, I2) do {                                          \
    const int kA = (wn + 2 * (I2)) & 7;                                 \
    const int kB = (wn + 2 * (I2) + 1) & 7;                             \
    const int kN = (wn + 2 * (I2) + 2) & 7;                             \
    if (PACKED) LOADB(Bb, kB); else LOADB_SLOW(Ba, kA);                 \
    CLUSTER(XF, HF, Ba, kA);                                            \
    if (PACKED) LOADB(Ba, kN); else LOADB_SLOW(Bb, kB);                 \
    CLUSTER(XF, HF, Bb, kB);                                            \
} while (0)

// full tile: 4 K-pairs with next-tile DMA staging woven in, fused epilogue
#define TILE_BODY(XF, HF, XW, HW, TILE, PF) do {                        \
    const bool pf_ = (PF);                                              \
    const size_t prow0 = (size_t)((TILE) + 1) * BM;                     \
    _Pragma("unroll")                                                   \
    for (int mf = 0; mf < 2; ++mf)                                      \
        _Pragma("unroll")                                               \
        for (int nf = 0; nf < 2; ++nf) {                                \
            az[mf][nf] = (f32x4)0.0f; ar[mf][nf] = (f32x4)0.0f;         \
            anx[mf][nf] = (f32x4)0.0f; anh[mf][nf] = (f32x4)0.0f;       \
        }                                                               \
    KPAIR(XF, HF, 0);                                                   \
    if (pf_) { STAGE2(XW, HW, 0); STAGE2(XW, HW, 1); }                  \
    KPAIR(XF, HF, 1);                                                   \
    if (pf_) { STAGE2(XW, HW, 2); STAGE2(XW, HW, 3); }                  \
    KPAIR(XF, HF, 2);                                                   \
    KPAIR(XF, HF, 3);                                                   \
    const size_t row0 = (size_t)(TILE) * BM;                            \
    _Pragma("unroll")                                                   \
    for (int mf = 0; mf < 2; ++mf)                                      \
        _Pragma("unroll")                                               \
        for (int nf = 0; nf < 2; ++nf)                                  \
            _Pragma("unroll")                                           \
            for (int i = 0; i < 4; ++i) {                               \
                int rl  = mf * 16 + lg * 4 + i;                         \
                int col = wn * 32 + nf * 16 + lr;                       \
                float z  = 1.0f / (1.0f + __expf(-(az[mf][nf][i] + bz[nf]))); \
                float r  = 1.0f / (1.0f + __expf(-(ar[mf][nf][i] + br[nf]))); \
                float e2 = __expf(2.0f * (anx[mf][nf][i] + bnx[nf] + r * (anh[mf][nf][i] + bnh[nf]))); \
                float g  = 1.0f - 2.0f / (e2 + 1.0f);                   \
                float hp = (HF)[rl * ROWF + 4 * ((col >> 2) ^ (rl & 7)) + (col & 3)]; \
                __builtin_nontemporal_store((1.0f - z) * g + z * hp,    \
                    out + (row0 + rl) * HID + col);                     \
            }                                                           \
} while (0)

// ---- fused GRU cell ---------------------------------------------------------
// 256 persistent blocks (1/CU), 8 waves, 2/SIMD. BM=32 tiles; x/h kept as
// FP32 in LDS (4 buffers, 128KB), double-buffered and staged tile-ahead via
// global_load_lds (zero VGPR cost). B streams from the packed L2-resident
// fragment buffer with the proven Ba/Bb register pipeline. bf16 conversion
// happens at A-fragment load (cvt_pk, hidden under MFMA).
template<bool PACKED>
__global__ void __launch_bounds__(512, 2) gru_fused(
    const float* __restrict__ x,  const float* __restrict__ h,
    const __bf16* __restrict__ wb,
    const float* __restrict__ w_ir, const float* __restrict__ w_iz,
    const float* __restrict__ w_in, const float* __restrict__ w_hz,
    const float* __restrict__ w_hn,
    const float* __restrict__ b_ir, const float* __restrict__ b_iz,
    const float* __restrict__ b_in, const float* __restrict__ b_hz,
    const float* __restrict__ b_hn,
    float* __restrict__ out)
{
    __shared__ float xf0[BM * ROWF], hf0[BM * ROWF];   // 4 x 32 KB = 128 KB
    __shared__ float xf1[BM * ROWF], hf1[BM * ROWF];

    const int t    = threadIdx.x;
    const int lane = t & 63;
    const int wn   = t >> 6;      // 0..7 : col slice AND K-start stagger
    const int lr   = lane & 15;
    const int lg   = lane >> 4;

    const float* wsrc[5] = { w_ir, w_iz, w_in, w_hz, w_hn };
    const __bf16* wbase = wb + wn * 1024 + lane * 8;

    bf16x8 Ba[10], Bb[10];
    f32x4 az[2][2], ar[2][2], anx[2][2], anh[2][2];   // 64 accs

    // biases (tile-invariant)
    float bz[2], br[2], bnx[2], bnh[2];
#pragma unroll
    for (int nf = 0; nf < 2; ++nf) {
        int col = wn * 32 + nf * 16 + lr;
        bz[nf]  = b_iz[col] + b_hz[col];
        br[nf]  = b_ir[col] + b_hz[col];
        bnx[nf] = b_in[col];
        bnh[nf] = b_hn[col];
    }

    const int tb = blockIdx.x * TPB;

    // ---- prologue: DMA-stage tile0 into buf0, prime B pipeline --------------
    {
        const size_t prow0 = (size_t)tb * BM;   // (STAGE2 uses prow0)
        STAGE2(xf0, hf0, 0); STAGE2(xf0, hf0, 1);
        STAGE2(xf0, hf0, 2); STAGE2(xf0, hf0, 3);
    }
    if (PACKED) LOADB(Ba, wn);
    __syncthreads();   // vmcnt(0) drain -> tile0 resident

    // ---- 8 tiles, compile-time buffer alternation ---------------------------
    for (int it2 = 0; it2 < TPB / 2; ++it2) {
        TILE_BODY(xf0, hf0, xf1, hf1, tb + it2 * 2, true);
        __syncthreads();
        TILE_BODY(xf1, hf1, xf0, hf0, tb + it2 * 2 + 1, it2 < TPB / 2 - 1);
        __syncthreads();
    }
}

extern "C" void kernel_launch(void* const* d_in, const int* in_sizes, int n_in,
                              void* d_out, int out_size, void* d_ws, size_t ws_size,
                              hipStream_t stream) {
    const float* x    = (const float*)d_in[0];
    const float* h    = (const float*)d_in[1];
    const float* w_ir = (const float*)d_in[2];
    const float* b_ir = (const float*)d_in[3];
    const float* w_iz = (const float*)d_in[4];
    const float* b_iz = (const float*)d_in[5];
    const float* w_in = (const float*)d_in[6];
    const float* b_in = (const float*)d_in[7];
    const float* w_hz = (const float*)d_in[8];
    const float* b_hz = (const float*)d_in[9];
    const float* w_hn = (const float*)d_in[10];
    const float* b_hn = (const float*)d_in[11];
    float* out = (float*)d_out;

    const int B    = in_sizes[0] / HID;                               // 65536
    const int nblk = (B / BM) / TPB;                                  // 256
    const size_t wb_bytes = (size_t)5 * HID * HID * sizeof(__bf16);   // 640 KB

    if (ws_size >= wb_bytes) {
        __bf16* wb = (__bf16*)d_ws;
        prepack_frag<<<160, 256, 0, stream>>>(w_ir, w_iz, w_in, w_hz, w_hn, wb);
        gru_fused<true><<<nblk, 512, 0, stream>>>(
            x, h, wb, nullptr, nullptr, nullptr, nullptr, nullptr,
            b_ir, b_iz, b_in, b_hz, b_hn, out);
    } else {
        gru_fused<false><<<nblk, 512, 0, stream>>>(
            x, h, nullptr, w_ir, w_iz, w_in, w_hz, w_hn,
            b_ir, b_iz, b_in, b_hz, b_hn, out);
    }
}